// Round 5
// baseline (1029.214 us; speedup 1.0000x reference)
//
#include <hip/hip_runtime.h>

#define NB 8
#define NP 24564
#define NCLS 80          // foreground classes
#define TOPK 400
#define KEEPK 200
#define OUTS 19
#define NCELL (OUTS * OUTS)   // 361
#define DETN (NCLS * TOPK)    // 32000 per batch
#define CKS 32008             // compact-key stride per batch (16B-aligned)
#define ROWS 64
#define CHUNKS ((NP + ROWS - 1) / ROWS)   // 384
#define CAP 1024
#define T0 0.972f   // collection gate: E[count]=688±26 in [512,1024]; exact fallback otherwise

__device__ __forceinline__ unsigned f2ord(float f) {
    unsigned u = __float_as_uint(f);
    return (u & 0x80000000u) ? ~u : (u | 0x80000000u);
}
__device__ __forceinline__ float ord2f(unsigned k) {
    unsigned u = (k & 0x80000000u) ? (k & 0x7fffffffu) : ~k;
    return __uint_as_float(u);
}
// 1024 bins over key top-16-bits; valid scores (0.01,1] map to [0x23,0x380].
__device__ __forceinline__ unsigned bin16(unsigned key) {
    int b = (int)(key >> 16) - 0xBC00;
    b = b < 0 ? 0 : (b > 1023 ? 1023 : b);
    return (unsigned)b;
}

__device__ __forceinline__ void bitonic_desc(unsigned long long* cand, unsigned S, int tid) {
    for (unsigned k = 2; k <= S; k <<= 1)
        for (unsigned j = k >> 1; j; j >>= 1) {
            for (unsigned i = tid; i < S; i += 256) {
                unsigned l = i ^ j;
                if (l > i) {
                    unsigned long long a = cand[i], bq = cand[l];
                    bool sw = ((i & k) == 0) ? (a < bq) : (a > bq);
                    if (sw) { cand[i] = bq; cand[l] = a; }
                }
            }
            __syncthreads();
        }
}

// ---------------- kZ: zero counters + compact-key buffer -------------------
__global__ __launch_bounds__(256) void kZ(unsigned* __restrict__ gcnt,
                                          unsigned* __restrict__ cnt,
                                          unsigned long long* __restrict__ ckeys) {
    int t = blockIdx.x * 256 + threadIdx.x;
    if (t < NB * NCLS) gcnt[t] = 0u;
    if (t < NB) cnt[t] = 0u;
    for (int i = t; i < NB * CKS; i += 256 * 256) ckeys[i] = 0ull;
}

// ------- kA: decode boxes + direct threshold-collect (no transpose!) -------
__global__ __launch_bounds__(256) void kA(const float* __restrict__ x,
                                          float4* __restrict__ boxes,
                                          unsigned long long* __restrict__ gcand,
                                          unsigned* __restrict__ gcnt) {
    int blk = blockIdx.x;
    int b = blk / CHUNKS, chunk = blk % CHUNKS;
    int p0 = chunk * ROWS;
    int nrows = NP - p0; if (nrows > ROWS) nrows = ROWS;
    __shared__ float tile[ROWS * 93];
    const float* src = x + (size_t)(b * NP + p0) * 93;
    int total4 = (nrows * 93) >> 2;          // 64*93 and 52*93 both %4==0
    const float4* s4 = (const float4*)src;
    float4* t4 = (float4*)tile;
    for (int e = threadIdx.x; e < total4; e += 256) t4[e] = s4[e];
    __syncthreads();
    int row = threadIdx.x & 63;
    int cg = threadIdx.x >> 6;
    if (row < nrows) {
        unsigned p = (unsigned)(p0 + row);
        for (int c = cg; c < NCLS; c += 4) {   // c uniform per wave -> coalesced atomic
            float v = tile[row * 93 + 5 + c];
            if (v > T0) {                      // T0 > 0.01 -> mask irrelevant here
                unsigned key = f2ord(v);
                unsigned pos = atomicAdd(&gcnt[b * NCLS + c], 1u);
                if (pos < CAP)
                    gcand[(size_t)(b * NCLS + c) * CAP + pos] =
                        ((unsigned long long)key << 32) | (unsigned)(~p);
            }
        }
    }
    if (threadIdx.x < nrows) {
        const float* r = tile + threadIdx.x * 93;
        float l0 = r[0], l1 = r[1], l2 = r[2], l3 = r[3];
        float px1 = r[85], py1 = r[86], px2 = r[87], py2 = r[88];
        float v0 = r[89], v1 = r[90], v2 = r[91], v3 = r[92];
        float pw = px2 - px1, ph = py2 - py1;
        float pcx = 0.5f * (px2 + px1), pcy = 0.5f * (py2 + py1);
        float cx = l0 * pw * v0 + pcx;
        float cy = l1 * pw * v1 + pcy;      // reference uses pw here too
        float w = expf(l2 * v2) * pw;
        float h = expf(l3 * v3) * ph;
        float x1 = fminf(fmaxf(cx - 0.5f * w, 0.f), 1.f);
        float y1 = fminf(fmaxf(cy - 0.5f * h, 0.f), 1.f);
        float x2 = fminf(fmaxf(cx + 0.5f * w, 0.f), 1.f);
        float y2 = fminf(fmaxf(cy + 0.5f * h, 0.f), 1.f);
        boxes[(size_t)b * NP + p0 + threadIdx.x] = make_float4(x1, y1, x2, y2);
    }
}

// --- exact fallback select: strided masked read of x, hist1024 + refine ----
__device__ void select_strided(const float* __restrict__ src, unsigned needed,
                               unsigned long long* cand,
                               unsigned* hist, unsigned* aux, unsigned* scal,
                               int tid) {
    for (int i = tid; i < 1024; i += 256) hist[i] = 0u;
    if (tid == 0) { scal[0] = 0u; scal[1] = 0u; scal[2] = 0u; scal[3] = 0u; }
    __syncthreads();
    for (int p = tid; p < NP; p += 256) {
        float v = src[(size_t)p * 93];
        float m = (v > 0.01f) ? v : -1.0f;
        atomicAdd(&hist[bin16(f2ord(m))], 1u);
    }
    __syncthreads();
    unsigned h0 = hist[4 * tid], h1 = hist[4 * tid + 1];
    unsigned h2 = hist[4 * tid + 2], h3 = hist[4 * tid + 3];
    aux[tid] = h0 + h1 + h2 + h3;
    __syncthreads();
    for (int d = 1; d < 256; d <<= 1) {
        unsigned v = (tid + d < 256) ? aux[tid + d] : 0u;
        __syncthreads();
        aux[tid] += v;
        __syncthreads();
    }
    unsigned above = (tid < 255) ? aux[tid + 1] : 0u;
    unsigned s3 = above + h3, s2 = s3 + h2, s1 = s2 + h1, s0 = s1 + h0;
    if (s0 >= needed && s1 < needed) { scal[0] = 4 * tid;     scal[1] = s1;    scal[2] = s0; }
    if (s1 >= needed && s2 < needed) { scal[0] = 4 * tid + 1; scal[1] = s2;    scal[2] = s1; }
    if (s2 >= needed && s3 < needed) { scal[0] = 4 * tid + 2; scal[1] = s3;    scal[2] = s2; }
    if (s3 >= needed && above < needed) { scal[0] = 4 * tid + 3; scal[1] = above; scal[2] = s3; }
    __syncthreads();
    unsigned cb = scal[0], countHigh = scal[1], countAt = scal[2];
    unsigned cut8 = 0;
    if (countAt > CAP) {
        aux[tid] = 0u;
        __syncthreads();
        for (int p = tid; p < NP; p += 256) {
            float v = src[(size_t)p * 93];
            float m = (v > 0.01f) ? v : -1.0f;
            unsigned k = f2ord(m);
            if (bin16(k) == cb) atomicAdd(&aux[(k >> 8) & 255u], 1u);
        }
        __syncthreads();
        for (int d = 1; d < 256; d <<= 1) {
            unsigned v = (tid + d < 256) ? aux[tid + d] : 0u;
            __syncthreads();
            aux[tid] += v;
            __syncthreads();
        }
        unsigned suf8 = aux[tid];
        unsigned sufN = (tid < 255) ? aux[tid + 1] : 0u;
        unsigned need2 = needed - countHigh;
        if (suf8 >= need2 && sufN < need2) scal[3] = (unsigned)tid;
        __syncthreads();
        cut8 = scal[3];
    }
    __syncthreads();
    if (tid == 0) scal[1] = 0u;
    __syncthreads();
    for (int p = tid; p < NP; p += 256) {
        float v = src[(size_t)p * 93];
        float m = (v > 0.01f) ? v : -1.0f;
        unsigned key = f2ord(m);
        unsigned b16 = bin16(key);
        bool take = (b16 > cb) || (b16 == cb && ((key >> 8) & 255u) >= cut8);
        if (take) {
            unsigned pos = atomicAdd(&scal[1], 1u);
            if (pos < CAP) cand[pos] = ((unsigned long long)key << 32) | (unsigned)(~p);
        }
    }
    __syncthreads();
    unsigned cc = scal[1]; if (cc > CAP) cc = CAP;
    for (unsigned i = tid; i < CAP; i += 256) if (i >= cc) cand[i] = 0ull;
    __syncthreads();
    bitonic_desc(cand, (cc <= 512u) ? 512u : (unsigned)CAP, tid);
}

// -------- kNms: per (b,c) sort candidates, triangular IoU, NMS, compact ----
struct HistU { unsigned hist[1024]; unsigned aux[256]; };
union SelU { HistU s; unsigned iouRow[TOPK][13]; };

__global__ __launch_bounds__(256) void kNms(const float* __restrict__ x,
                                            const float4* __restrict__ boxes,
                                            const unsigned long long* __restrict__ gcand,
                                            const unsigned* __restrict__ gcnt,
                                            unsigned long long* __restrict__ ckeys,
                                            float4* __restrict__ cboxes,
                                            unsigned* __restrict__ cnt) {
    __shared__ unsigned long long cand[CAP];
    __shared__ float4 selBox[TOPK];
    __shared__ float selArea[TOPK];
    __shared__ unsigned scal[4];
    __shared__ SelU U;
    __shared__ unsigned keptWords[13];

    int b = blockIdx.x / NCLS, c = blockIdx.x % NCLS;
    int tid = threadIdx.x;
    unsigned n = gcnt[b * NCLS + c];

    if (n >= TOPK && n <= CAP) {          // fast path (block-uniform branch)
        const unsigned long long* g = gcand + (size_t)(b * NCLS + c) * CAP;
        for (int i = tid; i < CAP; i += 256) cand[i] = (i < (int)n) ? g[i] : 0ull;
        __syncthreads();
        bitonic_desc(cand, (n <= 512u) ? 512u : (unsigned)CAP, tid);
    } else {                              // exact fallback: strided sweep of x
        select_strided(x + (size_t)b * NP * 93 + 5 + c, TOPK,
                       cand, U.s.hist, U.s.aux, scal, tid);
    }

    for (int k = tid; k < TOPK; k += 256) {
        unsigned idx = ~(unsigned)cand[k];
        if (idx >= NP) idx = 0;
        float4 bx = boxes[(size_t)b * NP + idx];
        selBox[k] = bx;
        selArea[k] = (bx.z - bx.x) * (bx.w - bx.y);
    }
    __syncthreads();

    // triangular IoU: row r only needs words 0..(r>>5); rows paired (t,399-t).
    // Garbage words beyond are ANDed against zero kept-mask bits -> safe.
#pragma unroll 1
    for (int pass = 0; pass < 2; ++pass) {
        int r = (pass == 0) ? tid : 399 - tid;
        if (pass == 1 && tid >= 144) break;
        float4 br = selBox[r];
        float ar = selArea[r];
        int nw = (r >> 5) + 1;
        for (int w = 0; w < nw; ++w) {
            unsigned word = 0;
#pragma unroll 8
            for (int jj = 0; jj < 32; ++jj) {
                int j = w * 32 + jj;
                float4 bj = selBox[j];
                float ix = fminf(br.z, bj.z) - fmaxf(br.x, bj.x);
                float iy = fminf(br.w, bj.w) - fmaxf(br.y, bj.y);
                float inter = fmaxf(ix, 0.f) * fmaxf(iy, 0.f);
                float uni = ar + selArea[j] - inter;
                word |= (unsigned)(inter > 0.45f * uni) << jj;
            }
            U.iouRow[r][w] = word;
        }
    }
    __syncthreads();

    if (tid < 64) {                        // NMS scan, next-row LDS prefetch
        unsigned lane = tid;
        unsigned myKept = 0;
        const unsigned VALID_KEY = f2ord(0.01f);
        unsigned w = (lane < 13) ? U.iouRow[0][lane] : 0u;
        for (int i = 0; i < TOPK; ++i) {
            unsigned wn = (i < TOPK - 1 && lane < 13) ? U.iouRow[i + 1][lane] : 0u;
            bool hit = (w & myKept) != 0u;
            unsigned long long bal = __ballot(hit);
            unsigned keyi = (unsigned)(cand[i] >> 32);
            bool kept = (keyi > VALID_KEY) && (bal == 0ull);
            if (kept && lane == (unsigned)(i >> 5)) myKept |= 1u << (i & 31);
            w = wn;
        }
        if (lane < 13) keptWords[lane] = myKept;
    }
    __syncthreads();

    // compact epilogue: kept entries -> per-batch list; boxes scattered by flat
    size_t kb = (size_t)b * CKS;
    size_t bb = (size_t)b * DETN;
    for (int k = tid; k < TOPK; k += 256) {
        unsigned flat = (unsigned)(c * TOPK + k);
        cboxes[bb + flat] = selBox[k];
        bool kept = (keptWords[k >> 5] >> (k & 31)) & 1u;
        if (kept) {
            unsigned key = (unsigned)(cand[k] >> 32);
            unsigned pos = atomicAdd(&cnt[b], 1u);
            ckeys[kb + pos] = ((unsigned long long)key << 32) | (unsigned)(~flat);
        }
    }
}

// -------- kC: per-batch top-200 of compacted keys + rasterize --------------
// Compacted scores concentrate in ~6 bin16 bins -> byte refine is MANDATORY.
__global__ __launch_bounds__(256) void kC(const unsigned long long* __restrict__ ckeys,
                                          const float4* __restrict__ cboxes,
                                          const unsigned* __restrict__ cnt,
                                          float* __restrict__ out) {
    __shared__ unsigned long long cand[CAP];
    __shared__ HistU S;
    __shared__ unsigned scal[4];
    __shared__ float eS[KEEPK];
    __shared__ int eC0[KEEPK], eC1[KEEPK], eC2[KEEPK], eC3[KEEPK];
    __shared__ int eCh[KEEPK];

    int b = blockIdx.x;
    int tid = threadIdx.x;
    const ulonglong2* k2 = (const ulonglong2*)(ckeys + (size_t)b * CKS);
    int n = (int)cnt[b]; if (n > DETN) n = DETN;
    int n2 = (n + 1) >> 1;           // buffer pre-zeroed by kZ -> safe pair reads
    const unsigned needed = KEEPK;

    for (int i = tid; i < 1024; i += 256) S.hist[i] = 0u;
    if (tid == 0) { scal[0] = 0u; scal[1] = 0u; scal[2] = 0u; scal[3] = 0u; }
    __syncthreads();
    for (int i = tid; i < n2; i += 256) {
        ulonglong2 v = k2[i];
        atomicAdd(&S.hist[bin16((unsigned)(v.x >> 32))], 1u);
        atomicAdd(&S.hist[bin16((unsigned)(v.y >> 32))], 1u);
    }
    __syncthreads();
    unsigned h0 = S.hist[4 * tid], h1 = S.hist[4 * tid + 1];
    unsigned h2 = S.hist[4 * tid + 2], h3 = S.hist[4 * tid + 3];
    S.aux[tid] = h0 + h1 + h2 + h3;
    __syncthreads();
    for (int d = 1; d < 256; d <<= 1) {
        unsigned v = (tid + d < 256) ? S.aux[tid + d] : 0u;
        __syncthreads();
        S.aux[tid] += v;
        __syncthreads();
    }
    unsigned above = (tid < 255) ? S.aux[tid + 1] : 0u;
    unsigned s3 = above + h3, s2 = s3 + h2, s1 = s2 + h1, s0 = s1 + h0;
    if (s0 >= needed && s1 < needed) { scal[0] = 4 * tid;     scal[1] = s1;    scal[2] = s0; }
    if (s1 >= needed && s2 < needed) { scal[0] = 4 * tid + 1; scal[1] = s2;    scal[2] = s1; }
    if (s2 >= needed && s3 < needed) { scal[0] = 4 * tid + 2; scal[1] = s3;    scal[2] = s2; }
    if (s3 >= needed && above < needed) { scal[0] = 4 * tid + 3; scal[1] = above; scal[2] = s3; }
    __syncthreads();
    unsigned cb = scal[0], countHigh = scal[1], countAt = scal[2];
    unsigned cut8 = 0;
    if (countAt > CAP) {   // byte refine on key[15:8] within cut bin
        S.aux[tid] = 0u;
        __syncthreads();
        for (int i = tid; i < n2; i += 256) {
            ulonglong2 v = k2[i];
            unsigned kx = (unsigned)(v.x >> 32), ky = (unsigned)(v.y >> 32);
            if (bin16(kx) == cb) atomicAdd(&S.aux[(kx >> 8) & 255u], 1u);
            if (bin16(ky) == cb) atomicAdd(&S.aux[(ky >> 8) & 255u], 1u);
        }
        __syncthreads();
        for (int d = 1; d < 256; d <<= 1) {
            unsigned v = (tid + d < 256) ? S.aux[tid + d] : 0u;
            __syncthreads();
            S.aux[tid] += v;
            __syncthreads();
        }
        unsigned suf8 = S.aux[tid];
        unsigned sufN = (tid < 255) ? S.aux[tid + 1] : 0u;
        unsigned need2 = needed - countHigh;
        if (suf8 >= need2 && sufN < need2) scal[3] = (unsigned)tid;
        __syncthreads();
        cut8 = scal[3];
    }
    __syncthreads();
    if (tid == 0) scal[1] = 0u;
    __syncthreads();
    for (int i = tid; i < n2; i += 256) {
        ulonglong2 v = k2[i];
#pragma unroll
        for (int c = 0; c < 2; ++c) {
            unsigned long long key = c ? v.y : v.x;
            unsigned kh = (unsigned)(key >> 32);
            unsigned b16 = bin16(kh);
            bool take = (b16 > cb) || (b16 == cb && ((kh >> 8) & 255u) >= cut8);
            if (take) {
                unsigned pos = atomicAdd(&scal[1], 1u);
                if (pos < CAP) cand[pos] = key;
            }
        }
    }
    __syncthreads();
    unsigned cc = scal[1]; if (cc > CAP) cc = CAP;
    for (unsigned i = tid; i < CAP; i += 256) if (i >= cc) cand[i] = 0ull;
    __syncthreads();
    bitonic_desc(cand, (cc <= 512u) ? 512u : (unsigned)CAP, tid);

    for (int k = tid; k < KEEPK; k += 256) {
        unsigned long long K = cand[k];
        unsigned key = (unsigned)(K >> 32);
        unsigned flat = ~(unsigned)K;
        if (flat >= DETN) flat = 0;
        float4 bx = cboxes[(size_t)b * DETN + flat];
        eS[k] = (key == 0u) ? -1.0f : ord2f(key);
        eC0[k] = (int)rintf(bx.x * (float)OUTS);
        eC1[k] = (int)rintf(bx.y * (float)OUTS);
        eC2[k] = (int)rintf(bx.z * (float)OUTS);
        eC3[k] = (int)rintf(bx.w * (float)OUTS);
        eCh[k] = (int)(flat / TOPK);
    }
    __syncthreads();

    for (int cell = tid; cell < NCELL; cell += 256) {
        int y = cell / OUTS, x = cell % OUTS;
        float* o = out + ((size_t)b * NCELL + cell) * 81;
        for (int ch = 0; ch < 81; ++ch) o[ch] = 0.f;
        for (int k = 0; k < KEEPK; ++k) {
            float s = eS[k];
            if (s < 0.6f) continue;
            if (y >= eC1[k] && y < eC3[k] && x >= eC0[k] && x < eC2[k])
                o[eCh[k]] = s;
        }
    }
}

extern "C" void kernel_launch(void* const* d_in, const int* in_sizes, int n_in,
                              void* d_out, int out_size, void* d_ws, size_t ws_size,
                              hipStream_t stream) {
    const float* x = (const float*)d_in[0];
    float* out = (float*)d_out;

    float4* boxes   = (float4*)d_ws;                          // NB*NP
    float4* cboxes  = boxes + (size_t)NB * NP;                // NB*DETN
    unsigned long long* ckeys = (unsigned long long*)(cboxes + (size_t)NB * DETN); // NB*CKS
    unsigned long long* gcand = ckeys + (size_t)NB * CKS;     // NB*NCLS*CAP
    unsigned* gcnt  = (unsigned*)(gcand + (size_t)NB * NCLS * CAP);  // NB*NCLS
    unsigned* cnt   = gcnt + NB * NCLS;                       // NB

    kZ<<<256, 256, 0, stream>>>(gcnt, cnt, ckeys);
    kA<<<NB * CHUNKS, 256, 0, stream>>>(x, boxes, gcand, gcnt);
    kNms<<<NB * NCLS, 256, 0, stream>>>(x, boxes, gcand, gcnt, ckeys, cboxes, cnt);
    kC<<<NB, 256, 0, stream>>>(ckeys, cboxes, cnt, out);
}

// Round 6
// 321.382 us; speedup vs baseline: 3.2025x; 3.2025x over previous
//
#include <hip/hip_runtime.h>

#define NB 8
#define NP 24564
#define NCLS 80          // foreground classes
#define TOPK 400
#define KEEPK 200
#define OUTS 19
#define NCELL (OUTS * OUTS)   // 361
#define DETN (NCLS * TOPK)    // 32000 per batch
#define CKS 32008             // compact-key stride per batch (16B-aligned)
#define ROWS 64
#define CHUNKS ((NP + ROWS - 1) / ROWS)   // 384
#define CAP 1024
#define T0 0.972f   // collection gate: E[count]=688 sd 26 -> count in [400,1024] w.h.p.
#define SLOTS 12    // per (chunk,class) capacity: P(Binom(64,0.028)>12) ~ 5e-8
#define SLOTN (CHUNKS * SLOTS)   // 4608 slots per (b,c)

__device__ __forceinline__ unsigned f2ord(float f) {
    unsigned u = __float_as_uint(f);
    return (u & 0x80000000u) ? ~u : (u | 0x80000000u);
}
__device__ __forceinline__ float ord2f(unsigned k) {
    unsigned u = (k & 0x80000000u) ? (k & 0x7fffffffu) : ~k;
    return __uint_as_float(u);
}
// 1024 bins over key top-16-bits; valid scores (0.01,1] map to [0x23,0x380].
__device__ __forceinline__ unsigned bin16(unsigned key) {
    int b = (int)(key >> 16) - 0xBC00;
    b = b < 0 ? 0 : (b > 1023 ? 1023 : b);
    return (unsigned)b;
}

__device__ __forceinline__ void bitonic_desc(unsigned long long* cand, unsigned S, int tid) {
    for (unsigned k = 2; k <= S; k <<= 1)
        for (unsigned j = k >> 1; j; j >>= 1) {
            for (unsigned i = tid; i < S; i += 256) {
                unsigned l = i ^ j;
                if (l > i) {
                    unsigned long long a = cand[i], bq = cand[l];
                    bool sw = ((i & k) == 0) ? (a < bq) : (a > bq);
                    if (sw) { cand[i] = bq; cand[l] = a; }
                }
            }
            __syncthreads();
        }
}

// ------- kZ: zero slot buffer, compact keys, flags, counters ---------------
__global__ __launch_bounds__(256) void kZ(unsigned long long* __restrict__ gcand,
                                          unsigned long long* __restrict__ ckeys,
                                          unsigned* __restrict__ gflag,
                                          unsigned* __restrict__ cnt) {
    int t = blockIdx.x * 256 + threadIdx.x;
    for (size_t i = t; i < (size_t)NB * NCLS * SLOTN; i += (size_t)gridDim.x * 256)
        gcand[i] = 0ull;
    if (t < NB * CKS) { /* covered below */ }
    for (int i = t; i < NB * CKS; i += gridDim.x * 256) ckeys[i] = 0ull;
    if (t < NB * NCLS) gflag[t] = 0u;
    if (t < NB * 16) cnt[t] = 0u;
}

// ------- kA: decode boxes + deterministic slot-collect (NO atomics) --------
__global__ __launch_bounds__(256) void kA(const float* __restrict__ x,
                                          float4* __restrict__ boxes,
                                          unsigned long long* __restrict__ gcand,
                                          unsigned* __restrict__ gflag) {
    int blk = blockIdx.x;
    int b = blk / CHUNKS, chunk = blk % CHUNKS;
    int p0 = chunk * ROWS;
    int nrows = NP - p0; if (nrows > ROWS) nrows = ROWS;
    __shared__ float tile[ROWS * 93];
    const float* src = x + (size_t)(b * NP + p0) * 93;
    int total4 = (nrows * 93) >> 2;          // 64*93 and 52*93 both %4==0
    const float4* s4 = (const float4*)src;
    float4* t4 = (float4*)tile;
    for (int e = threadIdx.x; e < total4; e += 256) t4[e] = s4[e];
    __syncthreads();
    int row = threadIdx.x & 63;              // lane == row
    int lane = row;
    int cg = threadIdx.x >> 6;
    unsigned p = (unsigned)(p0 + row);
    bool rowOk = row < nrows;
    for (int c = cg; c < NCLS; c += 4) {     // c uniform per wave
        float v = rowOk ? tile[row * 93 + 5 + c] : -1.0f;
        bool pred = v > T0;
        unsigned long long bal = __ballot(pred);
        unsigned rank = (unsigned)__popcll(bal & ((1ull << lane) - 1ull));
        if (pred && rank < SLOTS) {
            unsigned key = f2ord(v);
            gcand[((size_t)(b * NCLS + c) * CHUNKS + chunk) * SLOTS + rank] =
                ((unsigned long long)key << 32) | (unsigned)(~p);
        }
        if (lane == 0 && __popcll(bal) > SLOTS) gflag[b * NCLS + c] = 1u;
    }
    if (threadIdx.x < nrows) {
        const float* r = tile + threadIdx.x * 93;
        float l0 = r[0], l1 = r[1], l2 = r[2], l3 = r[3];
        float px1 = r[85], py1 = r[86], px2 = r[87], py2 = r[88];
        float v0 = r[89], v1 = r[90], v2 = r[91], v3 = r[92];
        float pw = px2 - px1, ph = py2 - py1;
        float pcx = 0.5f * (px2 + px1), pcy = 0.5f * (py2 + py1);
        float cx = l0 * pw * v0 + pcx;
        float cy = l1 * pw * v1 + pcy;      // reference uses pw here too
        float w = expf(l2 * v2) * pw;
        float h = expf(l3 * v3) * ph;
        float x1 = fminf(fmaxf(cx - 0.5f * w, 0.f), 1.f);
        float y1 = fminf(fmaxf(cy - 0.5f * h, 0.f), 1.f);
        float x2 = fminf(fmaxf(cx + 0.5f * w, 0.f), 1.f);
        float y2 = fminf(fmaxf(cy + 0.5f * h, 0.f), 1.f);
        boxes[(size_t)b * NP + p0 + threadIdx.x] = make_float4(x1, y1, x2, y2);
    }
}

// --- exact fallback select: strided masked read of x, hist1024 + refine ----
__device__ void select_strided(const float* __restrict__ src, unsigned needed,
                               unsigned long long* cand,
                               unsigned* hist, unsigned* aux, unsigned* scal,
                               int tid) {
    for (int i = tid; i < 1024; i += 256) hist[i] = 0u;
    if (tid == 0) { scal[0] = 0u; scal[1] = 0u; scal[2] = 0u; scal[3] = 0u; }
    __syncthreads();
    for (int p = tid; p < NP; p += 256) {
        float v = src[(size_t)p * 93];
        float m = (v > 0.01f) ? v : -1.0f;
        atomicAdd(&hist[bin16(f2ord(m))], 1u);
    }
    __syncthreads();
    unsigned h0 = hist[4 * tid], h1 = hist[4 * tid + 1];
    unsigned h2 = hist[4 * tid + 2], h3 = hist[4 * tid + 3];
    aux[tid] = h0 + h1 + h2 + h3;
    __syncthreads();
    for (int d = 1; d < 256; d <<= 1) {
        unsigned v = (tid + d < 256) ? aux[tid + d] : 0u;
        __syncthreads();
        aux[tid] += v;
        __syncthreads();
    }
    unsigned above = (tid < 255) ? aux[tid + 1] : 0u;
    unsigned s3 = above + h3, s2 = s3 + h2, s1 = s2 + h1, s0 = s1 + h0;
    if (s0 >= needed && s1 < needed) { scal[0] = 4 * tid;     scal[1] = s1;    scal[2] = s0; }
    if (s1 >= needed && s2 < needed) { scal[0] = 4 * tid + 1; scal[1] = s2;    scal[2] = s1; }
    if (s2 >= needed && s3 < needed) { scal[0] = 4 * tid + 2; scal[1] = s3;    scal[2] = s2; }
    if (s3 >= needed && above < needed) { scal[0] = 4 * tid + 3; scal[1] = above; scal[2] = s3; }
    __syncthreads();
    unsigned cb = scal[0], countHigh = scal[1], countAt = scal[2];
    unsigned cut8 = 0;
    if (countAt > CAP) {
        aux[tid] = 0u;
        __syncthreads();
        for (int p = tid; p < NP; p += 256) {
            float v = src[(size_t)p * 93];
            float m = (v > 0.01f) ? v : -1.0f;
            unsigned k = f2ord(m);
            if (bin16(k) == cb) atomicAdd(&aux[(k >> 8) & 255u], 1u);
        }
        __syncthreads();
        for (int d = 1; d < 256; d <<= 1) {
            unsigned v = (tid + d < 256) ? aux[tid + d] : 0u;
            __syncthreads();
            aux[tid] += v;
            __syncthreads();
        }
        unsigned suf8 = aux[tid];
        unsigned sufN = (tid < 255) ? aux[tid + 1] : 0u;
        unsigned need2 = needed - countHigh;
        if (suf8 >= need2 && sufN < need2) scal[3] = (unsigned)tid;
        __syncthreads();
        cut8 = scal[3];
    }
    __syncthreads();
    if (tid == 0) scal[1] = 0u;
    __syncthreads();
    for (int p = tid; p < NP; p += 256) {
        float v = src[(size_t)p * 93];
        float m = (v > 0.01f) ? v : -1.0f;
        unsigned key = f2ord(m);
        unsigned b16 = bin16(key);
        bool take = (b16 > cb) || (b16 == cb && ((key >> 8) & 255u) >= cut8);
        if (take) {
            unsigned pos = atomicAdd(&scal[1], 1u);
            if (pos < CAP) cand[pos] = ((unsigned long long)key << 32) | (unsigned)(~p);
        }
    }
    __syncthreads();
    unsigned cc = scal[1]; if (cc > CAP) cc = CAP;
    for (unsigned i = tid; i < CAP; i += 256) if (i >= cc) cand[i] = 0ull;
    __syncthreads();
    bitonic_desc(cand, (cc <= 512u) ? 512u : (unsigned)CAP, tid);
}

// -------- kNms: compact slots, sort, triangular IoU, NMS, compact out ------
struct HistU { unsigned hist[1024]; unsigned aux[256]; };
union SelU { HistU s; unsigned iouRow[TOPK][13]; };

__global__ __launch_bounds__(256) void kNms(const float* __restrict__ x,
                                            const float4* __restrict__ boxes,
                                            const unsigned long long* __restrict__ gcand,
                                            const unsigned* __restrict__ gflag,
                                            unsigned long long* __restrict__ ckeys,
                                            float4* __restrict__ cboxes,
                                            unsigned* __restrict__ cnt) {
    __shared__ unsigned long long cand[CAP];
    __shared__ float4 selBox[TOPK];
    __shared__ float selArea[TOPK];
    __shared__ unsigned scal[4];
    __shared__ SelU U;
    __shared__ unsigned keptWords[13];

    int b = blockIdx.x / NCLS, c = blockIdx.x % NCLS;
    int tid = threadIdx.x;

    // compact nonzero slots into cand
    if (tid == 0) scal[1] = 0u;
    __syncthreads();
    const ulonglong2* g2 = (const ulonglong2*)(gcand + (size_t)(b * NCLS + c) * SLOTN);
    for (int i = tid; i < SLOTN / 2; i += 256) {
        ulonglong2 v = g2[i];
        if (v.x) { unsigned pos = atomicAdd(&scal[1], 1u); if (pos < CAP) cand[pos] = v.x; }
        if (v.y) { unsigned pos = atomicAdd(&scal[1], 1u); if (pos < CAP) cand[pos] = v.y; }
    }
    __syncthreads();
    unsigned count = scal[1];
    bool fast = (gflag[b * NCLS + c] == 0u) && (count >= TOPK) && (count <= CAP);
    if (fast) {
        for (unsigned i = tid; i < CAP; i += 256) if (i >= count) cand[i] = 0ull;
        __syncthreads();
        bitonic_desc(cand, (count <= 512u) ? 512u : (unsigned)CAP, tid);
    } else {    // exact fallback (probability ~5e-8 per launch)
        __syncthreads();
        select_strided(x + (size_t)b * NP * 93 + 5 + c, TOPK,
                       cand, U.s.hist, U.s.aux, scal, tid);
    }

    for (int k = tid; k < TOPK; k += 256) {
        unsigned idx = ~(unsigned)cand[k];
        if (idx >= NP) idx = 0;
        float4 bx = boxes[(size_t)b * NP + idx];
        selBox[k] = bx;
        selArea[k] = (bx.z - bx.x) * (bx.w - bx.y);
    }
    __syncthreads();

    // triangular IoU: row r only needs words 0..(r>>5); rows paired (t,399-t).
    // Garbage words beyond are ANDed against zero kept-mask bits -> safe.
#pragma unroll 1
    for (int pass = 0; pass < 2; ++pass) {
        int r = (pass == 0) ? tid : 399 - tid;
        if (pass == 1 && tid >= 144) break;
        float4 br = selBox[r];
        float ar = selArea[r];
        int nw = (r >> 5) + 1;
        for (int w = 0; w < nw; ++w) {
            unsigned word = 0;
#pragma unroll 8
            for (int jj = 0; jj < 32; ++jj) {
                int j = w * 32 + jj;
                float4 bj = selBox[j];
                float ix = fminf(br.z, bj.z) - fmaxf(br.x, bj.x);
                float iy = fminf(br.w, bj.w) - fmaxf(br.y, bj.y);
                float inter = fmaxf(ix, 0.f) * fmaxf(iy, 0.f);
                float uni = ar + selArea[j] - inter;
                word |= (unsigned)(inter > 0.45f * uni) << jj;
            }
            U.iouRow[r][w] = word;
        }
    }
    __syncthreads();

    if (tid < 64) {                        // NMS scan, next-row LDS prefetch
        unsigned lane = tid;
        unsigned myKept = 0;
        const unsigned VALID_KEY = f2ord(0.01f);
        unsigned w = (lane < 13) ? U.iouRow[0][lane] : 0u;
        for (int i = 0; i < TOPK; ++i) {
            unsigned wn = (i < TOPK - 1 && lane < 13) ? U.iouRow[i + 1][lane] : 0u;
            bool hit = (w & myKept) != 0u;
            unsigned long long bal = __ballot(hit);
            unsigned keyi = (unsigned)(cand[i] >> 32);
            bool kept = (keyi > VALID_KEY) && (bal == 0ull);
            if (kept && lane == (unsigned)(i >> 5)) myKept |= 1u << (i & 31);
            w = wn;
        }
        if (lane < 13) keptWords[lane] = myKept;
    }
    __syncthreads();

    // epilogue: ONE reservation atomic per block, rank-indexed writes
    if (tid == 0) {
        unsigned total = 0;
        for (int w = 0; w < 13; ++w) total += __popc(keptWords[w]);
        scal[2] = atomicAdd(&cnt[b * 16], total);
    }
    __syncthreads();
    unsigned base = scal[2];
    size_t kb = (size_t)b * CKS;
    size_t bb = (size_t)b * DETN;
    for (int k = tid; k < TOPK; k += 256) {
        unsigned flat = (unsigned)(c * TOPK + k);
        cboxes[bb + flat] = selBox[k];
        bool kept = (keptWords[k >> 5] >> (k & 31)) & 1u;
        if (kept) {
            unsigned rank = 0;
            int wi = k >> 5;
            for (int w = 0; w < wi; ++w) rank += __popc(keptWords[w]);
            rank += __popc(keptWords[wi] & ((1u << (k & 31)) - 1u));
            unsigned key = (unsigned)(cand[k] >> 32);
            ckeys[kb + base + rank] = ((unsigned long long)key << 32) | (unsigned)(~flat);
        }
    }
}

// -------- kC: per-batch top-200 of compacted keys + rasterize --------------
// Compacted scores concentrate in ~6 bin16 bins -> byte refine is MANDATORY.
__global__ __launch_bounds__(256) void kC(const unsigned long long* __restrict__ ckeys,
                                          const float4* __restrict__ cboxes,
                                          const unsigned* __restrict__ cnt,
                                          float* __restrict__ out) {
    __shared__ unsigned long long cand[CAP];
    __shared__ HistU S;
    __shared__ unsigned scal[4];
    __shared__ float eS[KEEPK];
    __shared__ int eC0[KEEPK], eC1[KEEPK], eC2[KEEPK], eC3[KEEPK];
    __shared__ int eCh[KEEPK];

    int b = blockIdx.x;
    int tid = threadIdx.x;
    const ulonglong2* k2 = (const ulonglong2*)(ckeys + (size_t)b * CKS);
    int n = (int)cnt[b * 16]; if (n > DETN) n = DETN;
    int n2 = (n + 1) >> 1;           // buffer pre-zeroed by kZ -> safe pair reads
    const unsigned needed = KEEPK;

    for (int i = tid; i < 1024; i += 256) S.hist[i] = 0u;
    if (tid == 0) { scal[0] = 0u; scal[1] = 0u; scal[2] = 0u; scal[3] = 0u; }
    __syncthreads();
    for (int i = tid; i < n2; i += 256) {
        ulonglong2 v = k2[i];
        atomicAdd(&S.hist[bin16((unsigned)(v.x >> 32))], 1u);
        atomicAdd(&S.hist[bin16((unsigned)(v.y >> 32))], 1u);
    }
    __syncthreads();
    unsigned h0 = S.hist[4 * tid], h1 = S.hist[4 * tid + 1];
    unsigned h2 = S.hist[4 * tid + 2], h3 = S.hist[4 * tid + 3];
    S.aux[tid] = h0 + h1 + h2 + h3;
    __syncthreads();
    for (int d = 1; d < 256; d <<= 1) {
        unsigned v = (tid + d < 256) ? S.aux[tid + d] : 0u;
        __syncthreads();
        S.aux[tid] += v;
        __syncthreads();
    }
    unsigned above = (tid < 255) ? S.aux[tid + 1] : 0u;
    unsigned s3 = above + h3, s2 = s3 + h2, s1 = s2 + h1, s0 = s1 + h0;
    if (s0 >= needed && s1 < needed) { scal[0] = 4 * tid;     scal[1] = s1;    scal[2] = s0; }
    if (s1 >= needed && s2 < needed) { scal[0] = 4 * tid + 1; scal[1] = s2;    scal[2] = s1; }
    if (s2 >= needed && s3 < needed) { scal[0] = 4 * tid + 2; scal[1] = s3;    scal[2] = s2; }
    if (s3 >= needed && above < needed) { scal[0] = 4 * tid + 3; scal[1] = above; scal[2] = s3; }
    __syncthreads();
    unsigned cb = scal[0], countHigh = scal[1], countAt = scal[2];
    unsigned cut8 = 0;
    if (countAt > CAP) {   // byte refine on key[15:8] within cut bin
        S.aux[tid] = 0u;
        __syncthreads();
        for (int i = tid; i < n2; i += 256) {
            ulonglong2 v = k2[i];
            unsigned kx = (unsigned)(v.x >> 32), ky = (unsigned)(v.y >> 32);
            if (bin16(kx) == cb) atomicAdd(&S.aux[(kx >> 8) & 255u], 1u);
            if (bin16(ky) == cb) atomicAdd(&S.aux[(ky >> 8) & 255u], 1u);
        }
        __syncthreads();
        for (int d = 1; d < 256; d <<= 1) {
            unsigned v = (tid + d < 256) ? S.aux[tid + d] : 0u;
            __syncthreads();
            S.aux[tid] += v;
            __syncthreads();
        }
        unsigned suf8 = S.aux[tid];
        unsigned sufN = (tid < 255) ? S.aux[tid + 1] : 0u;
        unsigned need2 = needed - countHigh;
        if (suf8 >= need2 && sufN < need2) scal[3] = (unsigned)tid;
        __syncthreads();
        cut8 = scal[3];
    }
    __syncthreads();
    if (tid == 0) scal[1] = 0u;
    __syncthreads();
    for (int i = tid; i < n2; i += 256) {
        ulonglong2 v = k2[i];
#pragma unroll
        for (int c = 0; c < 2; ++c) {
            unsigned long long key = c ? v.y : v.x;
            unsigned kh = (unsigned)(key >> 32);
            unsigned b16 = bin16(kh);
            bool take = (b16 > cb) || (b16 == cb && ((kh >> 8) & 255u) >= cut8);
            if (take) {
                unsigned pos = atomicAdd(&scal[1], 1u);
                if (pos < CAP) cand[pos] = key;
            }
        }
    }
    __syncthreads();
    unsigned cc = scal[1]; if (cc > CAP) cc = CAP;
    for (unsigned i = tid; i < CAP; i += 256) if (i >= cc) cand[i] = 0ull;
    __syncthreads();
    bitonic_desc(cand, (cc <= 512u) ? 512u : (unsigned)CAP, tid);

    for (int k = tid; k < KEEPK; k += 256) {
        unsigned long long K = cand[k];
        unsigned key = (unsigned)(K >> 32);
        unsigned flat = ~(unsigned)K;
        if (flat >= DETN) flat = 0;
        float4 bx = cboxes[(size_t)b * DETN + flat];
        eS[k] = (key == 0u) ? -1.0f : ord2f(key);
        eC0[k] = (int)rintf(bx.x * (float)OUTS);
        eC1[k] = (int)rintf(bx.y * (float)OUTS);
        eC2[k] = (int)rintf(bx.z * (float)OUTS);
        eC3[k] = (int)rintf(bx.w * (float)OUTS);
        eCh[k] = (int)(flat / TOPK);
    }
    __syncthreads();

    for (int cell = tid; cell < NCELL; cell += 256) {
        int y = cell / OUTS, x = cell % OUTS;
        float* o = out + ((size_t)b * NCELL + cell) * 81;
        for (int ch = 0; ch < 81; ++ch) o[ch] = 0.f;
        for (int k = 0; k < KEEPK; ++k) {
            float s = eS[k];
            if (s < 0.6f) continue;
            if (y >= eC1[k] && y < eC3[k] && x >= eC0[k] && x < eC2[k])
                o[eCh[k]] = s;
        }
    }
}

extern "C" void kernel_launch(void* const* d_in, const int* in_sizes, int n_in,
                              void* d_out, int out_size, void* d_ws, size_t ws_size,
                              hipStream_t stream) {
    const float* x = (const float*)d_in[0];
    float* out = (float*)d_out;

    float4* boxes   = (float4*)d_ws;                          // NB*NP
    float4* cboxes  = boxes + (size_t)NB * NP;                // NB*DETN
    unsigned long long* ckeys = (unsigned long long*)(cboxes + (size_t)NB * DETN); // NB*CKS
    unsigned long long* gcand = ckeys + (size_t)NB * CKS;     // NB*NCLS*SLOTN
    unsigned* gflag = (unsigned*)(gcand + (size_t)NB * NCLS * SLOTN);  // NB*NCLS
    unsigned* cnt   = gflag + NB * NCLS;                      // NB*16 (cacheline-padded)

    kZ<<<2048, 256, 0, stream>>>(gcand, ckeys, gflag, cnt);
    kA<<<NB * CHUNKS, 256, 0, stream>>>(x, boxes, gcand, gflag);
    kNms<<<NB * NCLS, 256, 0, stream>>>(x, boxes, gcand, gflag, ckeys, cboxes, cnt);
    kC<<<NB, 256, 0, stream>>>(ckeys, cboxes, cnt, out);
}